// Round 10
// baseline (533.450 us; speedup 1.0000x reference)
//
#include <hip/hip_runtime.h>
#include <math.h>

// Fused CNN classifier: conv(1->8,3x3,s2,p1)+ReLU -> conv(8->16,3x3,s2,p1)+ReLU
//                       -> FC(784->1) -> softplus+0.001 -> 1-exp(-r) -> clip
// B=65536 images of 1x28x28 fp32.
//
// R10: occupancy unlock. R9 (SSA-ify) dropped the kernel below the harness
// fill kernels (~<120us, was 158). Remaining theory: latency-bound, no pipe
// >15% per-SIMD, occupancy capped at 40% by LDS (simg+sz1 = 35.3KB -> 4
// blocks/CU). Fix: DELETE simg. conv1 taps read directly from global (image
// = 3.1KB, L1-resident; per row one aligned float2 + one float), borders
// via clamped addresses + 0/1 mask multiplies. LDS = sz1 only (18.2KB),
// __launch_bounds__(256,6) -> 6 blocks/CU = 24 waves/CU (1.5x TLP). Also
// kills conv1's LDS bank conflicts (was 4-way on odd banks) and the whole
// staging/prefetch path. Geometry recomputed per step to keep VGPR <= 84.
// Predicted: occupancy 40->60-75%, kernel dur -> 80-100us, bank conflicts
// 1.3e7 -> <=0.5e7, WRITE stays ~0 (jump => spill => relax bounds to 5).

typedef short bf16x8 __attribute__((ext_vector_type(8)));
typedef float f32x4  __attribute__((ext_vector_type(4)));

#define NBLOCKS 4096
#define Z1_RS 19                    // z1 row stride in 16B slots (odd!)
#define Z1_SLOTS (15 * Z1_RS)       // 285 slots per image

static __device__ __forceinline__ short f2bf(float f) {
    union { float f; unsigned u; } v; v.f = f;
    unsigned r = v.u + 0x7FFF + ((v.u >> 16) & 1);   // RNE (no NaN inputs)
    return (short)(r >> 16);
}

// One conv1 channel pair (CA, CA+1): 9-tap FMA + ReLU + pack to 2xbf16.
#define CONV1_PAIR(CA, PKDST) do {                                          \
    const float* wa_ = &W1[(CA) * 9];                                       \
    const float* wc_ = &W1[((CA) + 1) * 9];                                 \
    float za_ = b1[(CA)], zc_ = b1[(CA) + 1];                               \
    za_ = fmaf(t0, wa_[0], za_); zc_ = fmaf(t0, wc_[0], zc_);               \
    za_ = fmaf(t1, wa_[1], za_); zc_ = fmaf(t1, wc_[1], zc_);               \
    za_ = fmaf(t2, wa_[2], za_); zc_ = fmaf(t2, wc_[2], zc_);               \
    za_ = fmaf(t3, wa_[3], za_); zc_ = fmaf(t3, wc_[3], zc_);               \
    za_ = fmaf(t4, wa_[4], za_); zc_ = fmaf(t4, wc_[4], zc_);               \
    za_ = fmaf(t5, wa_[5], za_); zc_ = fmaf(t5, wc_[5], zc_);               \
    za_ = fmaf(t6, wa_[6], za_); zc_ = fmaf(t6, wc_[6], zc_);               \
    za_ = fmaf(t7, wa_[7], za_); zc_ = fmaf(t7, wc_[7], zc_);               \
    za_ = fmaf(t8, wa_[8], za_); zc_ = fmaf(t8, wc_[8], zc_);               \
    za_ = fmaxf(za_, 0.f);       zc_ = fmaxf(zc_, 0.f);                     \
    asm("v_cvt_pk_bf16_f32 %0, %1, %2" : "=v"(PKDST) : "v"(za_), "v"(zc_)); \
} while (0)

// One conv1 output position, taps read DIRECTLY from global image xi.
// Output pos (py,px) reads input rows 2py-1..2py+1, cols 2px-1..2px+1;
// row -1 / col -1 are pad-zeros: clamp the address, zero via 0/1 masks.
#define CONV1_STEP(I, STORE_COND) do {                                        \
    int p_ = (I) * 64 + lane; if (p_ > 195) p_ = 195;                         \
    int py_ = p_ / 14, px_ = p_ - py_ * 14;                                   \
    int r1_ = py_ * 56;                 /* (2py)*28   */                      \
    int r0_ = r1_ - 28; if (r0_ < 0) r0_ = 0;                                 \
    int r2_ = r1_ + 28;                                                       \
    int c1_ = px_ * 2;                                                        \
    int c0_ = c1_ - 1; if (c0_ < 0) c0_ = 0;                                  \
    float mt_  = (py_ > 0) ? 1.f : 0.f;                                       \
    float ml_  = (px_ > 0) ? 1.f : 0.f;                                       \
    float mtl_ = mt_ * ml_;                                                   \
    float2 a12 = *(const float2*)(xi + r0_ + c1_);   /* 8B-aligned */         \
    float  a0  = xi[r0_ + c0_];                                               \
    float2 b45 = *(const float2*)(xi + r1_ + c1_);                            \
    float  b3  = xi[r1_ + c0_];                                               \
    float2 c78 = *(const float2*)(xi + r2_ + c1_);                            \
    float  c6  = xi[r2_ + c0_];                                               \
    float t0 = a0 * mtl_, t1 = a12.x * mt_, t2 = a12.y * mt_;                 \
    float t3 = b3 * ml_,  t4 = b45.x,       t5 = b45.y;                       \
    float t6 = c6 * ml_,  t7 = c78.x,       t8 = c78.y;                       \
    asm volatile("" : "+v"(t0), "+v"(t1), "+v"(t2), "+v"(t3), "+v"(t4),       \
                      "+v"(t5), "+v"(t6), "+v"(t7), "+v"(t8));                \
    unsigned pk0_, pk1_, pk2_, pk3_;                                          \
    CONV1_PAIR(0, pk0_);                                                      \
    CONV1_PAIR(2, pk1_);                                                      \
    CONV1_PAIR(4, pk2_);                                                      \
    CONV1_PAIR(6, pk3_);                                                      \
    int zoff_ = ((py_ + 1) * Z1_RS + px_ + 1) * 16;                           \
    if (STORE_COND)                                                           \
        *(uint4*)(z1b + zoff_) = make_uint4(pk0_, pk1_, pk2_, pk3_);          \
} while (0)

__global__ __launch_bounds__(256, 6) void fused_cnn_mfma(
    const float* __restrict__ x,
    const float* __restrict__ W1, const float* __restrict__ b1,
    const float* __restrict__ W2, const float* __restrict__ b2,
    const float* __restrict__ Wfc, const float* __restrict__ bfc,
    float* __restrict__ out, int nimg)
{
    __shared__ bf16x8 sz1[4][Z1_SLOTS];                   // 18240 B only

    const int tid  = threadIdx.x;
    const int w    = tid >> 6;       // wave id = image slot (wave-private LDS)
    const int lane = tid & 63;
    const int hi   = lane >> 4;
    const int lo   = lane & 15;

    // ---------------- one-time setup (all wave-private, no barrier) --------
    {
        bf16x8 zz = {0,0,0,0,0,0,0,0};
        for (int i = lane; i < Z1_SLOTS; i += 64) sz1[w][i] = zz;
    }

    // B-frags: W2 as bf16, named regs. k = tap*8 + ic; lane(hi,lo):
    // B[k=kk*32+hi*8+j][n=lo] -> tap = kk*4+hi, ic=j. tap>=9 => 0 (K-pad).
    #define MK_WB(KK) ({                                                    \
        bf16x8 v_;                                                          \
        const int tap_ = (KK) * 4 + hi;                                     \
        _Pragma("unroll")                                                   \
        for (int j = 0; j < 8; j++)                                         \
            v_[j] = (tap_ < 9) ? f2bf(W2[lo * 72 + j * 9 + tap_])           \
                               : (short)0;                                  \
        v_; })
    const bf16x8 wb0 = MK_WB(0), wb1 = MK_WB(1), wb2 = MK_WB(2);

    // conv2 A-read byte offsets into sz1[w]: slot = (2qy+ty)*19 + (2qx+tx)
    #define MK_POSOFF(T) ({                                                 \
        int p_ = (T) * 16 + lo; if (p_ > 48) p_ = 48;                       \
        int qy_ = p_ / 7, qx_ = p_ - qy_ * 7;                               \
        ((2 * qy_) * Z1_RS + 2 * qx_) * 16; })
    const int posoff0 = MK_POSOFF(0), posoff1 = MK_POSOFF(1),
              posoff2 = MK_POSOFF(2), posoff3 = MK_POSOFF(3);
    #define MK_TAPOFF(KK) ({                                                \
        int tap_ = (KK) * 4 + hi;                                           \
        int ty_ = tap_ / 3, tx_ = tap_ - ty_ * 3;                           \
        (tap_ < 9) ? (ty_ * Z1_RS + tx_) * 16 : 0; })
    const int tapoff0 = MK_TAPOFF(0), tapoff1 = MK_TAPOFF(1),
              tapoff2 = MK_TAPOFF(2);

    // Epilogue constants: lane(hi,lo) holds D[pos=t*16+hi*4+r][c2=lo].
    const float b2v = b2[lo];
    #define MK_WFC(T) ({                                                    \
        f32x4 v_;                                                           \
        _Pragma("unroll")                                                   \
        for (int r = 0; r < 4; r++) {                                       \
            int p_ = (T) * 16 + hi * 4 + r;                                 \
            v_[r] = (p_ < 49) ? Wfc[lo * 49 + p_] : 0.f;                    \
        }                                                                   \
        v_; })
    const f32x4 wfct0 = MK_WFC(0), wfct1 = MK_WFC(1),
                wfct2 = MK_WFC(2), wfct3 = MK_WFC(3);
    const float bfc0 = bfc[0];

    const int nquad = (nimg + 3) >> 2;
    char* const z1b = (char*)&sz1[w][0];

    for (int q = blockIdx.x; q < nquad; q += gridDim.x) {
        int img = q * 4 + w;
        if (img >= nimg) img = nimg - 1;
        const float* __restrict__ xi = x + (size_t)img * 784;

        // ---- conv1 (fp32 VALU), taps direct from global (L1-resident) ----
        CONV1_STEP(0, 1);
        CONV1_STEP(1, 1);
        CONV1_STEP(2, 1);
        CONV1_STEP(3, lane < 4);

        // ---- conv2: 4 pos-tiles x 3 K-steps; A = z1 (one b128/frag) ----
        f32x4 acc0 = {0.f, 0.f, 0.f, 0.f};
        f32x4 acc1 = {0.f, 0.f, 0.f, 0.f};
        f32x4 acc2 = {0.f, 0.f, 0.f, 0.f};
        f32x4 acc3 = {0.f, 0.f, 0.f, 0.f};
        #define C2(ACC, POS) do {                                           \
            ACC = __builtin_amdgcn_mfma_f32_16x16x32_bf16(                  \
                *(const bf16x8*)(z1b + (POS) + tapoff0), wb0, ACC, 0, 0, 0);\
            ACC = __builtin_amdgcn_mfma_f32_16x16x32_bf16(                  \
                *(const bf16x8*)(z1b + (POS) + tapoff1), wb1, ACC, 0, 0, 0);\
            ACC = __builtin_amdgcn_mfma_f32_16x16x32_bf16(                  \
                *(const bf16x8*)(z1b + (POS) + tapoff2), wb2, ACC, 0, 0, 0);\
        } while (0)
        C2(acc0, posoff0);
        C2(acc1, posoff1);
        C2(acc2, posoff2);
        C2(acc3, posoff3);

        // ---- epilogue: bias+ReLU+FC fold, wave reduce, softplus ----
        float fc = 0.f;
        #define EPI(ACC, WF) do {                                           \
            _Pragma("unroll")                                               \
            for (int r = 0; r < 4; r++) {                                   \
                float z_ = fmaxf((ACC)[r] + b2v, 0.f);                      \
                fc = fmaf(z_, (WF)[r], fc);                                 \
            }                                                               \
        } while (0)
        EPI(acc0, wfct0);
        EPI(acc1, wfct1);
        EPI(acc2, wfct2);
        EPI(acc3, wfct3);
        #pragma unroll
        for (int off = 32; off > 0; off >>= 1)
            fc += __shfl_down(fc, off, 64);

        if (lane == 0) {
            int imgo = q * 4 + w;
            if (imgo < nimg) {
                float v    = fc + bfc0;
                float sp   = fmaxf(v, 0.f) + log1pf(expf(-fabsf(v)));
                float rate = sp + 0.001f;
                float pr   = 1.f - expf(-rate);
                out[imgo] = fminf(fmaxf(pr, 1e-6f), 1.f - 1e-6f);
            }
        }
    }
}

extern "C" void kernel_launch(void* const* d_in, const int* in_sizes, int n_in,
                              void* d_out, int out_size, void* d_ws, size_t ws_size,
                              hipStream_t stream) {
    const float* x   = (const float*)d_in[0];
    const float* W1  = (const float*)d_in[1];
    const float* b1  = (const float*)d_in[2];
    const float* W2  = (const float*)d_in[3];
    const float* b2  = (const float*)d_in[4];
    const float* Wfc = (const float*)d_in[5];
    const float* bfc = (const float*)d_in[6];
    float* out = (float*)d_out;

    const int nimg  = in_sizes[0] / 784;
    const int nquad = (nimg + 3) / 4;
    const int grid  = nquad < NBLOCKS ? nquad : NBLOCKS;

    fused_cnn_mfma<<<grid, 256, 0, stream>>>(x, W1, b1, W2, b2, Wfc, bfc,
                                             out, nimg);
}

// Round 11
// 341.658 us; speedup vs baseline: 1.5614x; 1.5614x over previous
//
#include <hip/hip_runtime.h>
#include <math.h>

// Fused CNN classifier: conv(1->8,3x3,s2,p1)+ReLU -> conv(8->16,3x3,s2,p1)+ReLU
//                       -> FC(784->1) -> softplus+0.001 -> 1-exp(-r) -> clip
// B=65536 images of 1x28x28 fp32.
//
// R11: un-spill R10. R10 (no-simg + bounds(256,6)) regressed 122->335us:
// WRITE_SIZE 283MB + FETCH 463MB + VGPR 40 = the allocator spilled the
// long-lived constants (wb/wfct/posoff/tapoff) to scratch to meet the
// 6-waves/EU (~80 VGPR) budget -- every q-iter reloads constants through
// scratch on the critical path. Single delta vs R10: __launch_bounds__
// back to (256,4) (128-VGPR budget, no spill; real usage ~70-90). LDS is
// still sz1-only (18.4KB) so blocks/CU is LDS-capped at 8; achieved
// occupancy = floor(512/VGPR) waves/EU >= 6 -> >=24 waves/CU (75%), the
// R10 occupancy goal without the scratch tax.
// Predicted: WRITE -> <=2MB, FETCH -> 210-240MB, VGPR -> 64-96, dur 335
// -> 80-110us (beats R9's ~122). If dur > 122 with WRITE~0: direct-global
// taps are the issue (L1 thrash) -> revert to R9+trimmed-LDS next.

typedef short bf16x8 __attribute__((ext_vector_type(8)));
typedef float f32x4  __attribute__((ext_vector_type(4)));

#define NBLOCKS 4096
#define Z1_RS 19                    // z1 row stride in 16B slots (odd!)
#define Z1_SLOTS (15 * Z1_RS)       // 285 slots per image

static __device__ __forceinline__ short f2bf(float f) {
    union { float f; unsigned u; } v; v.f = f;
    unsigned r = v.u + 0x7FFF + ((v.u >> 16) & 1);   // RNE (no NaN inputs)
    return (short)(r >> 16);
}

// One conv1 channel pair (CA, CA+1): 9-tap FMA + ReLU + pack to 2xbf16.
#define CONV1_PAIR(CA, PKDST) do {                                          \
    const float* wa_ = &W1[(CA) * 9];                                       \
    const float* wc_ = &W1[((CA) + 1) * 9];                                 \
    float za_ = b1[(CA)], zc_ = b1[(CA) + 1];                               \
    za_ = fmaf(t0, wa_[0], za_); zc_ = fmaf(t0, wc_[0], zc_);               \
    za_ = fmaf(t1, wa_[1], za_); zc_ = fmaf(t1, wc_[1], zc_);               \
    za_ = fmaf(t2, wa_[2], za_); zc_ = fmaf(t2, wc_[2], zc_);               \
    za_ = fmaf(t3, wa_[3], za_); zc_ = fmaf(t3, wc_[3], zc_);               \
    za_ = fmaf(t4, wa_[4], za_); zc_ = fmaf(t4, wc_[4], zc_);               \
    za_ = fmaf(t5, wa_[5], za_); zc_ = fmaf(t5, wc_[5], zc_);               \
    za_ = fmaf(t6, wa_[6], za_); zc_ = fmaf(t6, wc_[6], zc_);               \
    za_ = fmaf(t7, wa_[7], za_); zc_ = fmaf(t7, wc_[7], zc_);               \
    za_ = fmaf(t8, wa_[8], za_); zc_ = fmaf(t8, wc_[8], zc_);               \
    za_ = fmaxf(za_, 0.f);       zc_ = fmaxf(zc_, 0.f);                     \
    asm("v_cvt_pk_bf16_f32 %0, %1, %2" : "=v"(PKDST) : "v"(za_), "v"(zc_)); \
} while (0)

// One conv1 output position, taps read DIRECTLY from global image xi.
// Output pos (py,px) reads input rows 2py-1..2py+1, cols 2px-1..2px+1;
// row -1 / col -1 are pad-zeros: clamp the address, zero via 0/1 masks.
#define CONV1_STEP(I, STORE_COND) do {                                        \
    int p_ = (I) * 64 + lane; if (p_ > 195) p_ = 195;                         \
    int py_ = p_ / 14, px_ = p_ - py_ * 14;                                   \
    int r1_ = py_ * 56;                 /* (2py)*28   */                      \
    int r0_ = r1_ - 28; if (r0_ < 0) r0_ = 0;                                 \
    int r2_ = r1_ + 28;                                                       \
    int c1_ = px_ * 2;                                                        \
    int c0_ = c1_ - 1; if (c0_ < 0) c0_ = 0;                                  \
    float mt_  = (py_ > 0) ? 1.f : 0.f;                                       \
    float ml_  = (px_ > 0) ? 1.f : 0.f;                                       \
    float mtl_ = mt_ * ml_;                                                   \
    float2 a12 = *(const float2*)(xi + r0_ + c1_);   /* 8B-aligned */         \
    float  a0  = xi[r0_ + c0_];                                               \
    float2 b45 = *(const float2*)(xi + r1_ + c1_);                            \
    float  b3  = xi[r1_ + c0_];                                               \
    float2 c78 = *(const float2*)(xi + r2_ + c1_);                            \
    float  c6  = xi[r2_ + c0_];                                               \
    float t0 = a0 * mtl_, t1 = a12.x * mt_, t2 = a12.y * mt_;                 \
    float t3 = b3 * ml_,  t4 = b45.x,       t5 = b45.y;                       \
    float t6 = c6 * ml_,  t7 = c78.x,       t8 = c78.y;                       \
    asm volatile("" : "+v"(t0), "+v"(t1), "+v"(t2), "+v"(t3), "+v"(t4),       \
                      "+v"(t5), "+v"(t6), "+v"(t7), "+v"(t8));                \
    unsigned pk0_, pk1_, pk2_, pk3_;                                          \
    CONV1_PAIR(0, pk0_);                                                      \
    CONV1_PAIR(2, pk1_);                                                      \
    CONV1_PAIR(4, pk2_);                                                      \
    CONV1_PAIR(6, pk3_);                                                      \
    int zoff_ = ((py_ + 1) * Z1_RS + px_ + 1) * 16;                           \
    if (STORE_COND)                                                           \
        *(uint4*)(z1b + zoff_) = make_uint4(pk0_, pk1_, pk2_, pk3_);          \
} while (0)

__global__ __launch_bounds__(256, 4) void fused_cnn_mfma(
    const float* __restrict__ x,
    const float* __restrict__ W1, const float* __restrict__ b1,
    const float* __restrict__ W2, const float* __restrict__ b2,
    const float* __restrict__ Wfc, const float* __restrict__ bfc,
    float* __restrict__ out, int nimg)
{
    __shared__ bf16x8 sz1[4][Z1_SLOTS];                   // 18240 B only

    const int tid  = threadIdx.x;
    const int w    = tid >> 6;       // wave id = image slot (wave-private LDS)
    const int lane = tid & 63;
    const int hi   = lane >> 4;
    const int lo   = lane & 15;

    // ---------------- one-time setup (all wave-private, no barrier) --------
    {
        bf16x8 zz = {0,0,0,0,0,0,0,0};
        for (int i = lane; i < Z1_SLOTS; i += 64) sz1[w][i] = zz;
    }

    // B-frags: W2 as bf16, named regs. k = tap*8 + ic; lane(hi,lo):
    // B[k=kk*32+hi*8+j][n=lo] -> tap = kk*4+hi, ic=j. tap>=9 => 0 (K-pad).
    #define MK_WB(KK) ({                                                    \
        bf16x8 v_;                                                          \
        const int tap_ = (KK) * 4 + hi;                                     \
        _Pragma("unroll")                                                   \
        for (int j = 0; j < 8; j++)                                         \
            v_[j] = (tap_ < 9) ? f2bf(W2[lo * 72 + j * 9 + tap_])           \
                               : (short)0;                                  \
        v_; })
    const bf16x8 wb0 = MK_WB(0), wb1 = MK_WB(1), wb2 = MK_WB(2);

    // conv2 A-read byte offsets into sz1[w]: slot = (2qy+ty)*19 + (2qx+tx)
    #define MK_POSOFF(T) ({                                                 \
        int p_ = (T) * 16 + lo; if (p_ > 48) p_ = 48;                       \
        int qy_ = p_ / 7, qx_ = p_ - qy_ * 7;                               \
        ((2 * qy_) * Z1_RS + 2 * qx_) * 16; })
    const int posoff0 = MK_POSOFF(0), posoff1 = MK_POSOFF(1),
              posoff2 = MK_POSOFF(2), posoff3 = MK_POSOFF(3);
    #define MK_TAPOFF(KK) ({                                                \
        int tap_ = (KK) * 4 + hi;                                           \
        int ty_ = tap_ / 3, tx_ = tap_ - ty_ * 3;                           \
        (tap_ < 9) ? (ty_ * Z1_RS + tx_) * 16 : 0; })
    const int tapoff0 = MK_TAPOFF(0), tapoff1 = MK_TAPOFF(1),
              tapoff2 = MK_TAPOFF(2);

    // Epilogue constants: lane(hi,lo) holds D[pos=t*16+hi*4+r][c2=lo].
    const float b2v = b2[lo];
    #define MK_WFC(T) ({                                                    \
        f32x4 v_;                                                           \
        _Pragma("unroll")                                                   \
        for (int r = 0; r < 4; r++) {                                       \
            int p_ = (T) * 16 + hi * 4 + r;                                 \
            v_[r] = (p_ < 49) ? Wfc[lo * 49 + p_] : 0.f;                    \
        }                                                                   \
        v_; })
    const f32x4 wfct0 = MK_WFC(0), wfct1 = MK_WFC(1),
                wfct2 = MK_WFC(2), wfct3 = MK_WFC(3);
    const float bfc0 = bfc[0];

    const int nquad = (nimg + 3) >> 2;
    char* const z1b = (char*)&sz1[w][0];

    for (int q = blockIdx.x; q < nquad; q += gridDim.x) {
        int img = q * 4 + w;
        if (img >= nimg) img = nimg - 1;
        const float* __restrict__ xi = x + (size_t)img * 784;

        // ---- conv1 (fp32 VALU), taps direct from global (L1/L2-resident) ----
        CONV1_STEP(0, 1);
        CONV1_STEP(1, 1);
        CONV1_STEP(2, 1);
        CONV1_STEP(3, lane < 4);

        // ---- conv2: 4 pos-tiles x 3 K-steps; A = z1 (one b128/frag) ----
        f32x4 acc0 = {0.f, 0.f, 0.f, 0.f};
        f32x4 acc1 = {0.f, 0.f, 0.f, 0.f};
        f32x4 acc2 = {0.f, 0.f, 0.f, 0.f};
        f32x4 acc3 = {0.f, 0.f, 0.f, 0.f};
        #define C2(ACC, POS) do {                                           \
            ACC = __builtin_amdgcn_mfma_f32_16x16x32_bf16(                  \
                *(const bf16x8*)(z1b + (POS) + tapoff0), wb0, ACC, 0, 0, 0);\
            ACC = __builtin_amdgcn_mfma_f32_16x16x32_bf16(                  \
                *(const bf16x8*)(z1b + (POS) + tapoff1), wb1, ACC, 0, 0, 0);\
            ACC = __builtin_amdgcn_mfma_f32_16x16x32_bf16(                  \
                *(const bf16x8*)(z1b + (POS) + tapoff2), wb2, ACC, 0, 0, 0);\
        } while (0)
        C2(acc0, posoff0);
        C2(acc1, posoff1);
        C2(acc2, posoff2);
        C2(acc3, posoff3);

        // ---- epilogue: bias+ReLU+FC fold, wave reduce, softplus ----
        float fc = 0.f;
        #define EPI(ACC, WF) do {                                           \
            _Pragma("unroll")                                               \
            for (int r = 0; r < 4; r++) {                                   \
                float z_ = fmaxf((ACC)[r] + b2v, 0.f);                      \
                fc = fmaf(z_, (WF)[r], fc);                                 \
            }                                                               \
        } while (0)
        EPI(acc0, wfct0);
        EPI(acc1, wfct1);
        EPI(acc2, wfct2);
        EPI(acc3, wfct3);
        #pragma unroll
        for (int off = 32; off > 0; off >>= 1)
            fc += __shfl_down(fc, off, 64);

        if (lane == 0) {
            int imgo = q * 4 + w;
            if (imgo < nimg) {
                float v    = fc + bfc0;
                float sp   = fmaxf(v, 0.f) + log1pf(expf(-fabsf(v)));
                float rate = sp + 0.001f;
                float pr   = 1.f - expf(-rate);
                out[imgo] = fminf(fmaxf(pr, 1e-6f), 1.f - 1e-6f);
            }
        }
    }
}

extern "C" void kernel_launch(void* const* d_in, const int* in_sizes, int n_in,
                              void* d_out, int out_size, void* d_ws, size_t ws_size,
                              hipStream_t stream) {
    const float* x   = (const float*)d_in[0];
    const float* W1  = (const float*)d_in[1];
    const float* b1  = (const float*)d_in[2];
    const float* W2  = (const float*)d_in[3];
    const float* b2  = (const float*)d_in[4];
    const float* Wfc = (const float*)d_in[5];
    const float* bfc = (const float*)d_in[6];
    float* out = (float*)d_out;

    const int nimg  = in_sizes[0] / 784;
    const int nquad = (nimg + 3) / 4;
    const int grid  = nquad < NBLOCKS ? nquad : NBLOCKS;

    fused_cnn_mfma<<<grid, 256, 0, stream>>>(x, W1, b1, W2, b2, Wfc, bfc,
                                             out, nimg);
}